// Round 1
// baseline (954.869 us; speedup 1.0000x reference)
//
#include <hip/hip_runtime.h>
#include <cstdint>
#include <cstddef>

#define GBM 256
#define ASTR 260   // A_s row stride (256 + 4 pad): keeps float4 alignment, ~4-way store conflict max
#define WSTR 68    // W_s row stride (64 + 4 pad)

// ---------------- small prep kernels ----------------

__global__ void init_kernel(float* __restrict__ deg, int* __restrict__ cnt, int n) {
  int i = blockIdx.x * 256 + threadIdx.x;
  if (i < n) { deg[i] = 1.0f; cnt[i] = 0; }   // deg starts at 1.0 = self-loop weight
}

__global__ void degcnt_kernel(const int* __restrict__ ei, const float* __restrict__ ew,
                              float* __restrict__ deg, int* __restrict__ cnt, int E) {
  int e = blockIdx.x * 256 + threadIdx.x;
  if (e >= E) return;
  int col = ei[E + e];
  atomicAdd(&deg[col], ew[e]);
  atomicAdd(&cnt[col], 1);
}

__global__ void dinv_kernel(float* __restrict__ deg, int n) {
  int i = blockIdx.x * 256 + threadIdx.x;
  if (i < n) { float d = deg[i]; deg[i] = (d > 0.0f) ? rsqrtf(d) : 0.0f; }
}

// single-block chunked exclusive scan of cnt -> colp (and fillp copy)
__global__ __launch_bounds__(1024) void scan_kernel(const int* __restrict__ cnt,
                                                    int* __restrict__ colp,
                                                    int* __restrict__ fillp, int n) {
  __shared__ int wsum[16];
  __shared__ int carry_s;
  int tid = threadIdx.x, lane = tid & 63, wid = tid >> 6;
  if (tid == 0) carry_s = 0;
  __syncthreads();
  for (int base = 0; base < n; base += 1024) {
    int i = base + tid;
    int v = (i < n) ? cnt[i] : 0;
    int x = v;
    #pragma unroll
    for (int off = 1; off < 64; off <<= 1) {
      int y = __shfl_up(x, off);
      if (lane >= off) x += y;
    }
    if (lane == 63) wsum[wid] = x;
    __syncthreads();
    if (tid == 0) {
      int s = carry_s;
      #pragma unroll
      for (int w = 0; w < 16; ++w) { int t = wsum[w]; wsum[w] = s; s += t; }
      carry_s = s;
    }
    __syncthreads();
    int excl = wsum[wid] + x - v;
    if (i < n) { colp[i] = excl; fillp[i] = excl; }
    __syncthreads();
  }
  if (tid == 0) colp[n] = carry_s;
}

__global__ void fill_kernel(const int* __restrict__ ei, const float* __restrict__ ew,
                            const float* __restrict__ dinv, int* __restrict__ fillp,
                            int* __restrict__ csr_src, float* __restrict__ csr_w, int E) {
  int e = blockIdx.x * 256 + threadIdx.x;
  if (e >= E) return;
  int row = ei[e], col = ei[E + e];
  int pos = atomicAdd(&fillp[col], 1);
  csr_src[pos] = row;
  csr_w[pos] = dinv[row] * ew[e];   // pre-fold dinv[src]*ew; dinv[dst] applied at use
}

// Wf[k][c] = sum_m llm_proj_w[k][m] * conv1_w[80+m][c];  biasf[c] = sum_m pb[m]*conv1_w[80+m][c]
__global__ void prep_kernel(const float* __restrict__ pw, const float* __restrict__ pb,
                            const float* __restrict__ w1, float* __restrict__ Wf,
                            float* __restrict__ biasf) {
  int idx = blockIdx.x * 256 + threadIdx.x;
  if (idx < 768 * 64) {
    int k = idx >> 6, c = idx & 63;
    float acc = 0.0f;
    #pragma unroll 8
    for (int m = 0; m < 32; ++m) acc = fmaf(pw[k * 32 + m], w1[(80 + m) * 64 + c], acc);
    Wf[idx] = acc;
  } else if (idx < 768 * 64 + 64) {
    int c = idx - 768 * 64;
    float acc = 0.0f;
    for (int m = 0; m < 32; ++m) acc = fmaf(pb[m], w1[(80 + m) * 64 + c], acc);
    biasf[c] = acc;
  }
}

// ---------------- GEMM building block ----------------
// tile 256 rows x 64 cols, 256 threads, 8x8 acc per thread; A_s transposed [k][row]
__device__ __forceinline__ void mac_chunk(int KK, const float (*A_s)[ASTR],
                                          const float (*W_s)[WSTR],
                                          float (&acc)[8][8], int trow, int tcol) {
  #pragma unroll 4
  for (int k = 0; k < KK; ++k) {
    float a[8], w[8];
    *(float4*)&a[0] = *(const float4*)&A_s[k][trow * 8];
    *(float4*)&a[4] = *(const float4*)&A_s[k][trow * 8 + 4];
    *(float4*)&w[0] = *(const float4*)&W_s[k][tcol * 8];
    *(float4*)&w[4] = *(const float4*)&W_s[k][tcol * 8 + 4];
    #pragma unroll
    for (int i = 0; i < 8; ++i)
      #pragma unroll
      for (int j = 0; j < 8; ++j)
        acc[i][j] = fmaf(a[i], w[j], acc[i][j]);
  }
}

// fused feature-build + conv1 linear: out[n][64] (includes llm_proj_b contribution, NOT conv1_b)
__global__ __launch_bounds__(256) void gemm1_kernel(
    const float* __restrict__ llm, const float* __restrict__ Wf,
    const int* __restrict__ names, const int* __restrict__ types,
    const float* __restrict__ behav,
    const float* __restrict__ name_emb, const float* __restrict__ type_emb,
    const float* __restrict__ W1, const float* __restrict__ biasf,
    float* __restrict__ out, int n)
{
  __shared__ float A_s[32][ASTR];
  __shared__ float W_s[32][WSTR];
  __shared__ int names_s[GBM];
  __shared__ int types_s[GBM];
  const int tid = threadIdx.x;
  const int base = blockIdx.x * GBM;
  for (int i = tid; i < GBM; i += 256) {
    int node = base + i;
    names_s[i] = (node < n) ? names[node] : 0;
    types_s[i] = (node < n) ? types[node] : 0;
  }
  const int tcol = tid & 7;
  const int trow = tid >> 3;
  const int qa = tid & 7;    // k-quad id for staging (32-k chunks)
  const int ra = tid >> 3;   // row base for staging

  float acc[8][8];
  #pragma unroll
  for (int i = 0; i < 8; ++i)
    #pragma unroll
    for (int j = 0; j < 8; ++j) acc[i][j] = 0.0f;

  // ---- phase 1: llm @ Wf, 24 chunks of K=32 ----
  for (int kc = 0; kc < 24; ++kc) {
    const int k0 = kc * 32;
    __syncthreads();
    #pragma unroll
    for (int it = 0; it < 8; ++it) {
      int r = ra + it * 32;
      int node = base + r;
      float4 v = make_float4(0.f, 0.f, 0.f, 0.f);
      if (node < n) v = *(const float4*)(llm + (size_t)node * 768 + k0 + qa * 4);
      A_s[qa * 4 + 0][r] = v.x; A_s[qa * 4 + 1][r] = v.y;
      A_s[qa * 4 + 2][r] = v.z; A_s[qa * 4 + 3][r] = v.w;
    }
    #pragma unroll
    for (int it = 0; it < 2; ++it) {
      int q = tid + it * 256;
      int kk = q >> 4, cq = q & 15;
      *(float4*)&W_s[kk][cq * 4] = *(const float4*)(Wf + (size_t)(k0 + kk) * 64 + cq * 4);
    }
    __syncthreads();
    mac_chunk(32, (const float(*)[ASTR])A_s, (const float(*)[WSTR])W_s, acc, trow, tcol);
  }

  // ---- phase 2: name_emb gather, 2 chunks of K=32 (W1 rows 0..63) ----
  for (int kc = 0; kc < 2; ++kc) {
    const int koff = kc * 32;
    __syncthreads();
    #pragma unroll
    for (int it = 0; it < 8; ++it) {
      int r = ra + it * 32;
      float4 v = *(const float4*)(name_emb + (size_t)names_s[r] * 64 + koff + qa * 4);
      A_s[qa * 4 + 0][r] = v.x; A_s[qa * 4 + 1][r] = v.y;
      A_s[qa * 4 + 2][r] = v.z; A_s[qa * 4 + 3][r] = v.w;
    }
    #pragma unroll
    for (int it = 0; it < 2; ++it) {
      int q = tid + it * 256;
      int kk = q >> 4, cq = q & 15;
      *(float4*)&W_s[kk][cq * 4] = *(const float4*)(W1 + (size_t)(koff + kk) * 64 + cq * 4);
    }
    __syncthreads();
    mac_chunk(32, (const float(*)[ASTR])A_s, (const float(*)[WSTR])W_s, acc, trow, tcol);
  }

  // ---- phase 3: type_emb gather, 1 chunk of K=16 (W1 rows 64..79) ----
  {
    __syncthreads();
    int q4 = tid & 3, r4 = tid >> 2;
    #pragma unroll
    for (int it = 0; it < 4; ++it) {
      int r = r4 + it * 64;
      float4 v = *(const float4*)(type_emb + (size_t)types_s[r] * 16 + q4 * 4);
      A_s[q4 * 4 + 0][r] = v.x; A_s[q4 * 4 + 1][r] = v.y;
      A_s[q4 * 4 + 2][r] = v.z; A_s[q4 * 4 + 3][r] = v.w;
    }
    {
      int kk = tid >> 4, cq = tid & 15;
      *(float4*)&W_s[kk][cq * 4] = *(const float4*)(W1 + (size_t)(64 + kk) * 64 + cq * 4);
    }
    __syncthreads();
    mac_chunk(16, (const float(*)[ASTR])A_s, (const float(*)[WSTR])W_s, acc, trow, tcol);
  }

  // ---- phase 4: behaviors, 1 chunk of K=32 (W1 rows 112..143) ----
  {
    __syncthreads();
    #pragma unroll
    for (int it = 0; it < 8; ++it) {
      int r = ra + it * 32;
      int node = base + r;
      float4 v = make_float4(0.f, 0.f, 0.f, 0.f);
      if (node < n) v = *(const float4*)(behav + (size_t)node * 32 + qa * 4);
      A_s[qa * 4 + 0][r] = v.x; A_s[qa * 4 + 1][r] = v.y;
      A_s[qa * 4 + 2][r] = v.z; A_s[qa * 4 + 3][r] = v.w;
    }
    #pragma unroll
    for (int it = 0; it < 2; ++it) {
      int q = tid + it * 256;
      int kk = q >> 4, cq = q & 15;
      *(float4*)&W_s[kk][cq * 4] = *(const float4*)(W1 + (size_t)(112 + kk) * 64 + cq * 4);
    }
    __syncthreads();
    mac_chunk(32, (const float(*)[ASTR])A_s, (const float(*)[WSTR])W_s, acc, trow, tcol);
  }

  // store with biasf (llm_proj_b routed through W1)
  float bf[8];
  *(float4*)&bf[0] = *(const float4*)(biasf + tcol * 8);
  *(float4*)&bf[4] = *(const float4*)(biasf + tcol * 8 + 4);
  #pragma unroll
  for (int i = 0; i < 8; ++i) {
    int node = base + trow * 8 + i;
    if (node < n) {
      float4 v0, v1;
      v0.x = acc[i][0] + bf[0]; v0.y = acc[i][1] + bf[1];
      v0.z = acc[i][2] + bf[2]; v0.w = acc[i][3] + bf[3];
      v1.x = acc[i][4] + bf[4]; v1.y = acc[i][5] + bf[5];
      v1.z = acc[i][6] + bf[6]; v1.w = acc[i][7] + bf[7];
      *(float4*)(out + (size_t)node * 64 + tcol * 8) = v0;
      *(float4*)(out + (size_t)node * 64 + tcol * 8 + 4) = v1;
    }
  }
}

// conv2 linear: out = g1 @ W2  (64x64, no bias here)
__global__ __launch_bounds__(256) void gemm2_kernel(
    const float* __restrict__ g1, const float* __restrict__ W2,
    float* __restrict__ out, int n)
{
  __shared__ float A_s[32][ASTR];
  __shared__ float W_s[32][WSTR];
  const int tid = threadIdx.x;
  const int base = blockIdx.x * GBM;
  const int tcol = tid & 7, trow = tid >> 3;
  const int qa = tid & 7, ra = tid >> 3;

  float acc[8][8];
  #pragma unroll
  for (int i = 0; i < 8; ++i)
    #pragma unroll
    for (int j = 0; j < 8; ++j) acc[i][j] = 0.0f;

  for (int kc = 0; kc < 2; ++kc) {
    const int k0 = kc * 32;
    __syncthreads();
    #pragma unroll
    for (int it = 0; it < 8; ++it) {
      int r = ra + it * 32;
      int node = base + r;
      float4 v = make_float4(0.f, 0.f, 0.f, 0.f);
      if (node < n) v = *(const float4*)(g1 + (size_t)node * 64 + k0 + qa * 4);
      A_s[qa * 4 + 0][r] = v.x; A_s[qa * 4 + 1][r] = v.y;
      A_s[qa * 4 + 2][r] = v.z; A_s[qa * 4 + 3][r] = v.w;
    }
    #pragma unroll
    for (int it = 0; it < 2; ++it) {
      int q = tid + it * 256;
      int kk = q >> 4, cq = q & 15;
      *(float4*)&W_s[kk][cq * 4] = *(const float4*)(W2 + (size_t)(k0 + kk) * 64 + cq * 4);
    }
    __syncthreads();
    mac_chunk(32, (const float(*)[ASTR])A_s, (const float(*)[WSTR])W_s, acc, trow, tcol);
  }

  #pragma unroll
  for (int i = 0; i < 8; ++i) {
    int node = base + trow * 8 + i;
    if (node < n) {
      float4 v0, v1;
      v0.x = acc[i][0]; v0.y = acc[i][1]; v0.z = acc[i][2]; v0.w = acc[i][3];
      v1.x = acc[i][4]; v1.y = acc[i][5]; v1.z = acc[i][6]; v1.w = acc[i][7];
      *(float4*)(out + (size_t)node * 64 + tcol * 8) = v0;
      *(float4*)(out + (size_t)node * 64 + tcol * 8 + 4) = v1;
    }
  }
}

// aggregation: out[j] = relu(bias + dinv[j]^2*h[j] + sum_in dinv[src]*ew*dinv[j]*h[src])
// one wave per node; lane = channel
__global__ __launch_bounds__(256) void agg_kernel(
    const float* __restrict__ h, const int* __restrict__ colp,
    const int* __restrict__ csr_src, const float* __restrict__ csr_w,
    const float* __restrict__ dinv, const float* __restrict__ bias,
    float* __restrict__ out, int n)
{
  int wid = threadIdx.x >> 6, lane = threadIdx.x & 63;
  int j = blockIdx.x * 4 + wid;
  if (j >= n) return;
  float dj = dinv[j];
  float acc = bias[lane] + dj * dj * h[(size_t)j * 64 + lane];
  int e0 = colp[j], e1 = colp[j + 1];
  for (int e = e0; e < e1; ++e) {
    int s = csr_src[e];
    float c = csr_w[e] * dj;
    acc = fmaf(c, h[(size_t)s * 64 + lane], acc);
  }
  out[(size_t)j * 64 + lane] = fmaxf(acc, 0.0f);
}

// mean-pool per graph (batch is sorted): one block per graph
__global__ __launch_bounds__(256) void pool_kernel(const float* __restrict__ x,
                                                   const int* __restrict__ batch,
                                                   float* __restrict__ pooled, int n) {
  __shared__ float red[4][64];
  __shared__ int range_s[2];
  int g = blockIdx.x;
  int tid = threadIdx.x, wid = tid >> 6, lane = tid & 63;
  if (tid < 2) {
    int target = g + tid;
    int lo = 0, hi = n;
    while (lo < hi) { int m = (lo + hi) >> 1; if (batch[m] < target) lo = m + 1; else hi = m; }
    range_s[tid] = lo;
  }
  __syncthreads();
  int lo = range_s[0], hi = range_s[1];
  float acc = 0.0f;
  for (int i = lo + wid; i < hi; i += 4) acc += x[(size_t)i * 64 + lane];
  red[wid][lane] = acc;
  __syncthreads();
  if (tid < 64) {
    float s = red[0][lane] + red[1][lane] + red[2][lane] + red[3][lane];
    float cntf = (float)(hi - lo);
    pooled[g * 64 + lane] = s / fmaxf(cntf, 1.0f);
  }
}

__global__ void cls_kernel(const float* __restrict__ pooled, const float* __restrict__ cw,
                           const float* __restrict__ cb, float* __restrict__ out) {
  int t = threadIdx.x;          // 256 threads = 128 graphs x 2 classes
  int g = t >> 1, c = t & 1;
  float acc = cb[c];
  #pragma unroll 8
  for (int k = 0; k < 64; ++k) acc = fmaf(pooled[g * 64 + k], cw[k * 2 + c], acc);
  out[g * 2 + c] = acc;
}

// ---------------- launch ----------------

extern "C" void kernel_launch(void* const* d_in, const int* in_sizes, int n_in,
                              void* d_out, int out_size, void* d_ws, size_t ws_size,
                              hipStream_t stream) {
  const int*   x_names  = (const int*)  d_in[0];
  const int*   x_types  = (const int*)  d_in[1];
  const float* behav    = (const float*)d_in[2];
  const int*   ei       = (const int*)  d_in[3];
  const float* ew       = (const float*)d_in[4];
  const int*   batch    = (const int*)  d_in[5];
  const float* llm      = (const float*)d_in[6];
  const float* name_emb = (const float*)d_in[7];
  const float* type_emb = (const float*)d_in[8];
  const float* pw       = (const float*)d_in[9];
  const float* pb       = (const float*)d_in[10];
  const float* w1       = (const float*)d_in[11];
  const float* b1       = (const float*)d_in[12];
  const float* w2       = (const float*)d_in[13];
  const float* b2       = (const float*)d_in[14];
  const float* cw       = (const float*)d_in[15];
  const float* cb       = (const float*)d_in[16];

  const int N = in_sizes[0];
  const int E = in_sizes[4];

  char* p = (char*)d_ws;
  auto alloc = [&](size_t bytes) -> void* {
    void* r = (void*)p; p += (bytes + 255) & ~(size_t)255; return r;
  };
  float* deg    = (float*)alloc((size_t)N * 4);        // becomes dinv in-place
  int*   cnt    = (int*)  alloc((size_t)N * 4);
  int*   colp   = (int*)  alloc((size_t)(N + 1) * 4);
  int*   fillp  = (int*)  alloc((size_t)N * 4);
  int*   csr_s  = (int*)  alloc((size_t)E * 4);
  float* csr_w  = (float*)alloc((size_t)E * 4);
  float* Wf     = (float*)alloc((size_t)768 * 64 * 4);
  float* biasf  = (float*)alloc((size_t)64 * 4);
  float* bufX   = (float*)alloc((size_t)N * 64 * 4);
  float* bufY   = (float*)alloc((size_t)N * 64 * 4);
  float* pooled = (float*)alloc((size_t)128 * 64 * 4);
  (void)ws_size; (void)n_in; (void)out_size;

  const int nb = (N + 255) / 256;
  const int eb = (E + 255) / 256;
  const int tiles = (N + GBM - 1) / GBM;

  init_kernel<<<nb, 256, 0, stream>>>(deg, cnt, N);
  prep_kernel<<<(768 * 64 + 64 + 255) / 256, 256, 0, stream>>>(pw, pb, w1, Wf, biasf);
  degcnt_kernel<<<eb, 256, 0, stream>>>(ei, ew, deg, cnt, E);
  dinv_kernel<<<nb, 256, 0, stream>>>(deg, N);
  scan_kernel<<<1, 1024, 0, stream>>>(cnt, colp, fillp, N);
  fill_kernel<<<eb, 256, 0, stream>>>(ei, ew, deg, fillp, csr_s, csr_w, E);

  gemm1_kernel<<<tiles, 256, 0, stream>>>(llm, Wf, x_names, x_types, behav,
                                          name_emb, type_emb, w1, biasf, bufX, N);
  agg_kernel<<<(N + 3) / 4, 256, 0, stream>>>(bufX, colp, csr_s, csr_w, deg, b1, bufY, N);
  gemm2_kernel<<<tiles, 256, 0, stream>>>(bufY, w2, bufX, N);
  agg_kernel<<<(N + 3) / 4, 256, 0, stream>>>(bufX, colp, csr_s, csr_w, deg, b2, bufY, N);
  pool_kernel<<<128, 256, 0, stream>>>(bufY, batch, pooled, N);
  cls_kernel<<<1, 256, 0, stream>>>(pooled, cw, cb, (float*)d_out);
}

// Round 2
// 656.884 us; speedup vs baseline: 1.4536x; 1.4536x over previous
//
#include <hip/hip_runtime.h>
#include <cstdint>
#include <cstddef>

#define BM 128
#define APAD 36   // shorts per LDS row (32 + 4): 18*r mod 32 hits 16 distinct banks for r=0..15

typedef __attribute__((ext_vector_type(8))) short bf16x8;
typedef __attribute__((ext_vector_type(4))) float f32x4;

// ---------------- bf16 split helpers ----------------

__device__ __forceinline__ unsigned bf_rne(float x) {
  unsigned u = __float_as_uint(x);
  return (u + 0x7FFFu + ((u >> 16) & 1u)) >> 16;
}

__device__ __forceinline__ void split1(float x, short& hi, short& lo) {
  unsigned hb = bf_rne(x);
  hi = (short)hb;
  float fh = __uint_as_float(hb << 16);
  lo = (short)bf_rne(x - fh);
}

__device__ __forceinline__ void stage4(short* dh, short* dl, float4 v) {
  short4 h, l;
  split1(v.x, h.x, l.x); split1(v.y, h.y, l.y);
  split1(v.z, h.z, l.z); split1(v.w, h.w, l.w);
  *(short4*)dh = h; *(short4*)dl = l;
}

// fragment load: elems 0-3 = rowp[g*4..+3], elems 4-7 = rowp[16+g*4..+3]
// (same bijective k-slot map used for A and B -> permutation cancels)
__device__ __forceinline__ bf16x8 ldfrag(const short* rowp, int g) {
  short4 a = *(const short4*)(rowp + g * 4);
  short4 b = *(const short4*)(rowp + 16 + g * 4);
  bf16x8 f;
  f[0] = a.x; f[1] = a.y; f[2] = a.z; f[3] = a.w;
  f[4] = b.x; f[5] = b.y; f[6] = b.z; f[7] = b.w;
  return f;
}

// ---------------- prep: Wf = llm_proj_w @ conv1_w[80:112], biasf = pb @ conv1_w[80:112] ----------------

__global__ void prep_kernel(const float* __restrict__ pw, const float* __restrict__ pb,
                            const float* __restrict__ w1, float* __restrict__ Wf,
                            float* __restrict__ biasf) {
  int idx = blockIdx.x * 256 + threadIdx.x;
  if (idx < 768 * 64) {
    int k = idx >> 6, c = idx & 63;
    float acc = 0.0f;
    #pragma unroll 8
    for (int m = 0; m < 32; ++m) acc = fmaf(pw[k * 32 + m], w1[(80 + m) * 64 + c], acc);
    Wf[idx] = acc;
  } else if (idx < 768 * 64 + 64) {
    int c = idx - 768 * 64;
    float acc = 0.0f;
    for (int m = 0; m < 32; ++m) acc = fmaf(pb[m], w1[(80 + m) * 64 + c], acc);
    biasf[c] = acc;
  }
}

// ---------------- CSR build ----------------

__global__ void zero_kernel(int* __restrict__ cnt, int n) {
  int i = blockIdx.x * 256 + threadIdx.x;
  if (i < n) cnt[i] = 0;
}

__global__ void cnt_kernel(const int* __restrict__ ei, int* __restrict__ cnt, int E) {
  int e = blockIdx.x * 256 + threadIdx.x;
  if (e < E) atomicAdd(&cnt[ei[E + e]], 1);
}

__global__ __launch_bounds__(256) void scan_blk(const int* __restrict__ cnt,
                                                int* __restrict__ colp,
                                                int* __restrict__ bsum, int n) {
  __shared__ int ws[4];
  int t = threadIdx.x, lane = t & 63, w = t >> 6;
  int i = blockIdx.x * 256 + t;
  int v = (i < n) ? cnt[i] : 0;
  int x = v;
  #pragma unroll
  for (int off = 1; off < 64; off <<= 1) { int y = __shfl_up(x, off); if (lane >= off) x += y; }
  if (lane == 63) ws[w] = x;
  __syncthreads();
  if (t == 0) {
    int s = 0;
    #pragma unroll
    for (int k = 0; k < 4; ++k) { int tmp = ws[k]; ws[k] = s; s += tmp; }
    bsum[blockIdx.x] = s;
  }
  __syncthreads();
  if (i < n) colp[i] = ws[w] + x - v;
}

__global__ __launch_bounds__(512) void scan_top(int* __restrict__ bsum,
                                                int* __restrict__ colp, int nb, int n) {
  __shared__ int ws[8];
  int t = threadIdx.x, lane = t & 63, w = t >> 6;
  int v = (t < nb) ? bsum[t] : 0;
  int x = v;
  #pragma unroll
  for (int off = 1; off < 64; off <<= 1) { int y = __shfl_up(x, off); if (lane >= off) x += y; }
  if (lane == 63) ws[w] = x;
  __syncthreads();
  if (t == 0) {
    int s = 0;
    #pragma unroll
    for (int k = 0; k < 8; ++k) { int tmp = ws[k]; ws[k] = s; s += tmp; }
  }
  __syncthreads();
  int excl = ws[w] + x - v;
  if (t < nb) bsum[t] = excl;
  if (t == nb - 1) colp[n] = excl + v;
}

__global__ void scan_add(int* __restrict__ colp, int* __restrict__ fillp,
                         const int* __restrict__ bsum, int n) {
  int i = blockIdx.x * 256 + threadIdx.x;
  if (i < n) {
    int c = colp[i] + bsum[blockIdx.x];
    colp[i] = c;
    fillp[i] = c;
  }
}

__global__ void fill_kernel(const int* __restrict__ ei, const float* __restrict__ ew,
                            int* __restrict__ fillp, int2* __restrict__ csr, int E) {
  int e = blockIdx.x * 256 + threadIdx.x;
  if (e >= E) return;
  int row = ei[e], col = ei[E + e];
  int pos = atomicAdd(&fillp[col], 1);
  csr[pos] = make_int2(row, __float_as_int(ew[e]));
}

// dinv[j] = rsqrt(1 + sum of edge weights into j)  (coalesced CSR read, no float atomics)
__global__ void degsum_kernel(const int* __restrict__ colp, const int2* __restrict__ csr,
                              float* __restrict__ dinv, int n) {
  int j = blockIdx.x * 256 + threadIdx.x;
  if (j >= n) return;
  int e0 = colp[j], e1 = colp[j + 1];
  float s = 1.0f;
  for (int e = e0; e < e1; ++e) s += __int_as_float(csr[e].y);
  dinv[j] = rsqrtf(s);
}

__global__ void wfix_kernel(int2* __restrict__ csr, const float* __restrict__ dinv, int E) {
  int i = blockIdx.x * 256 + threadIdx.x;
  if (i >= E) return;
  int2 m = csr[i];
  csr[i] = make_int2(m.x, __float_as_int(__int_as_float(m.y) * dinv[m.x]));
}

// ---------------- gemm1: fused feature-build + conv1 linear (MFMA split-bf16) ----------------
// out[node][64] = [name|type|llm_proj|behav] @ W1 (+ llm_proj_b routed through W1), conv1_b added in agg

__global__ __launch_bounds__(256, 4) void gemm1_kernel(
    const float* __restrict__ llm, const float* __restrict__ Wf,
    const int* __restrict__ names, const int* __restrict__ types,
    const float* __restrict__ behav,
    const float* __restrict__ name_emb, const float* __restrict__ type_emb,
    const float* __restrict__ W1, const float* __restrict__ biasf,
    float* __restrict__ out, int n)
{
  __shared__ short Ah[BM][APAD], Al[BM][APAD];
  __shared__ short Wh[64][APAD], Wl[64][APAD];
  __shared__ int names_s[BM], types_s[BM];

  const int tid = threadIdx.x;
  const int base = blockIdx.x * BM;
  if (tid < BM) {
    int node = base + tid;
    names_s[tid] = (node < n) ? names[node] : 0;
    types_s[tid] = (node < n) ? types[node] : 0;
  }
  const int lane = tid & 63, wv = tid >> 6;
  const int g = lane >> 4, r16 = lane & 15;
  const int qa = tid & 7, ra = tid >> 3;      // A staging: kk=qa*4, rows ra+{0,32,64,96}
  const int wcol = tid & 63, wkg = tid >> 6;  // W staging: col, kk=wkg*8

  f32x4 acc[2][4];
  #pragma unroll
  for (int i = 0; i < 2; ++i)
    #pragma unroll
    for (int j = 0; j < 4; ++j) { acc[i][j][0] = 0.f; acc[i][j][1] = 0.f; acc[i][j][2] = 0.f; acc[i][j][3] = 0.f; }

  const float4 z4 = make_float4(0.f, 0.f, 0.f, 0.f);

  for (int chunk = 0; chunk < 28; ++chunk) {
    __syncthreads();
    // ---- stage A (128 rows x 32 k, f32 -> split bf16) ----
    #pragma unroll
    for (int it = 0; it < 4; ++it) {
      int row = ra + it * 32;
      int node = base + row;
      float4 v;
      if (chunk < 24) {
        v = (node < n) ? *(const float4*)(llm + (size_t)node * 768 + chunk * 32 + qa * 4) : z4;
      } else if (chunk < 26) {
        v = *(const float4*)(name_emb + (size_t)names_s[row] * 64 + (chunk - 24) * 32 + qa * 4);
      } else if (chunk == 26) {
        if (qa < 4) v = *(const float4*)(type_emb + (size_t)types_s[row] * 16 + qa * 4);
        else        v = (node < n) ? *(const float4*)(behav + (size_t)node * 32 + (qa - 4) * 4) : z4;
      } else {
        v = (qa < 4 && node < n) ? *(const float4*)(behav + (size_t)node * 32 + 16 + qa * 4) : z4;
      }
      stage4(&Ah[row][qa * 4], &Al[row][qa * 4], v);
    }
    // ---- stage W (32 k x 64 cols, transposed into [col][k]) ----
    {
      int kk = wkg * 8;
      short h8[8], l8[8];
      #pragma unroll
      for (int j = 0; j < 8; ++j) {
        int k = kk + j;
        float val;
        if (chunk < 24)       val = Wf[(size_t)(chunk * 32 + k) * 64 + wcol];
        else if (chunk < 26)  val = W1[(size_t)((chunk - 24) * 32 + k) * 64 + wcol];
        else if (chunk == 26) val = W1[(size_t)(k < 16 ? 64 + k : 96 + k) * 64 + wcol];
        else                  val = (k < 16) ? W1[(size_t)(128 + k) * 64 + wcol] : 0.f;
        split1(val, h8[j], l8[j]);
      }
      *(short4*)&Wh[wcol][kk]     = make_short4(h8[0], h8[1], h8[2], h8[3]);
      *(short4*)&Wh[wcol][kk + 4] = make_short4(h8[4], h8[5], h8[6], h8[7]);
      *(short4*)&Wl[wcol][kk]     = make_short4(l8[0], l8[1], l8[2], l8[3]);
      *(short4*)&Wl[wcol][kk + 4] = make_short4(l8[4], l8[5], l8[6], l8[7]);
    }
    __syncthreads();
    // ---- MFMA: 2 row-tiles x 4 col-tiles, 3 products each (hi*hi + hi*lo + lo*hi) ----
    bf16x8 bh[4], bl[4];
    #pragma unroll
    for (int ct = 0; ct < 4; ++ct) {
      int col = ct * 16 + r16;
      bh[ct] = ldfrag(&Wh[col][0], g);
      bl[ct] = ldfrag(&Wl[col][0], g);
    }
    #pragma unroll
    for (int rt = 0; rt < 2; ++rt) {
      int arow = (wv * 2 + rt) * 16 + r16;
      bf16x8 ah = ldfrag(&Ah[arow][0], g);
      bf16x8 al = ldfrag(&Al[arow][0], g);
      #pragma unroll
      for (int ct = 0; ct < 4; ++ct) {
        acc[rt][ct] = __builtin_amdgcn_mfma_f32_16x16x32_bf16(ah, bh[ct], acc[rt][ct], 0, 0, 0);
        acc[rt][ct] = __builtin_amdgcn_mfma_f32_16x16x32_bf16(ah, bl[ct], acc[rt][ct], 0, 0, 0);
        acc[rt][ct] = __builtin_amdgcn_mfma_f32_16x16x32_bf16(al, bh[ct], acc[rt][ct], 0, 0, 0);
      }
    }
  }

  // ---- store: D[row][col], col = lane&15 (+16*ct), row = (lane>>4)*4 + reg ----
  #pragma unroll
  for (int ct = 0; ct < 4; ++ct) {
    int col = ct * 16 + r16;
    float bf = biasf[col];
    #pragma unroll
    for (int rt = 0; rt < 2; ++rt) {
      #pragma unroll
      for (int rr = 0; rr < 4; ++rr) {
        int node = base + (wv * 2 + rt) * 16 + g * 4 + rr;
        if (node < n) out[(size_t)node * 64 + col] = acc[rt][ct][rr] + bf;
      }
    }
  }
}

// ---------------- gemm2: h @ W2 (MFMA split-bf16), K=64 ----------------

__global__ __launch_bounds__(256, 4) void gemm2_kernel(
    const float* __restrict__ g1, const float* __restrict__ W2,
    float* __restrict__ out, int n)
{
  __shared__ short Ah[BM][APAD], Al[BM][APAD];
  __shared__ short Wh[64][APAD], Wl[64][APAD];

  const int tid = threadIdx.x;
  const int base = blockIdx.x * BM;
  const int lane = tid & 63, wv = tid >> 6;
  const int g = lane >> 4, r16 = lane & 15;
  const int qa = tid & 7, ra = tid >> 3;
  const int wcol = tid & 63, wkg = tid >> 6;

  f32x4 acc[2][4];
  #pragma unroll
  for (int i = 0; i < 2; ++i)
    #pragma unroll
    for (int j = 0; j < 4; ++j) { acc[i][j][0] = 0.f; acc[i][j][1] = 0.f; acc[i][j][2] = 0.f; acc[i][j][3] = 0.f; }

  const float4 z4 = make_float4(0.f, 0.f, 0.f, 0.f);

  #pragma unroll
  for (int chunk = 0; chunk < 2; ++chunk) {
    __syncthreads();
    #pragma unroll
    for (int it = 0; it < 4; ++it) {
      int row = ra + it * 32;
      int node = base + row;
      float4 v = (node < n) ? *(const float4*)(g1 + (size_t)node * 64 + chunk * 32 + qa * 4) : z4;
      stage4(&Ah[row][qa * 4], &Al[row][qa * 4], v);
    }
    {
      int kk = wkg * 8;
      short h8[8], l8[8];
      #pragma unroll
      for (int j = 0; j < 8; ++j) split1(W2[(size_t)(chunk * 32 + kk + j) * 64 + wcol], h8[j], l8[j]);
      *(short4*)&Wh[wcol][kk]     = make_short4(h8[0], h8[1], h8[2], h8[3]);
      *(short4*)&Wh[wcol][kk + 4] = make_short4(h8[4], h8[5], h8[6], h8[7]);
      *(short4*)&Wl[wcol][kk]     = make_short4(l8[0], l8[1], l8[2], l8[3]);
      *(short4*)&Wl[wcol][kk + 4] = make_short4(l8[4], l8[5], l8[6], l8[7]);
    }
    __syncthreads();
    bf16x8 bh[4], bl[4];
    #pragma unroll
    for (int ct = 0; ct < 4; ++ct) {
      int col = ct * 16 + r16;
      bh[ct] = ldfrag(&Wh[col][0], g);
      bl[ct] = ldfrag(&Wl[col][0], g);
    }
    #pragma unroll
    for (int rt = 0; rt < 2; ++rt) {
      int arow = (wv * 2 + rt) * 16 + r16;
      bf16x8 ah = ldfrag(&Ah[arow][0], g);
      bf16x8 al = ldfrag(&Al[arow][0], g);
      #pragma unroll
      for (int ct = 0; ct < 4; ++ct) {
        acc[rt][ct] = __builtin_amdgcn_mfma_f32_16x16x32_bf16(ah, bh[ct], acc[rt][ct], 0, 0, 0);
        acc[rt][ct] = __builtin_amdgcn_mfma_f32_16x16x32_bf16(ah, bl[ct], acc[rt][ct], 0, 0, 0);
        acc[rt][ct] = __builtin_amdgcn_mfma_f32_16x16x32_bf16(al, bh[ct], acc[rt][ct], 0, 0, 0);
      }
    }
  }

  #pragma unroll
  for (int ct = 0; ct < 4; ++ct) {
    int col = ct * 16 + r16;
    #pragma unroll
    for (int rt = 0; rt < 2; ++rt) {
      #pragma unroll
      for (int rr = 0; rr < 4; ++rr) {
        int node = base + (wv * 2 + rt) * 16 + g * 4 + rr;
        if (node < n) out[(size_t)node * 64 + col] = acc[rt][ct][rr];
      }
    }
  }
}

// ---------------- aggregation: out[j] = relu(bias + dj*(dj*h[j] + sum_in w*h[src])) ----------------
// one wave per node; lane = channel; csr_w pre-folded with dinv[src]

__global__ __launch_bounds__(256) void agg_kernel(
    const float* __restrict__ h, const int* __restrict__ colp,
    const int2* __restrict__ csr, const float* __restrict__ dinv,
    const float* __restrict__ bias, float* __restrict__ out, int n)
{
  int wid = threadIdx.x >> 6, lane = threadIdx.x & 63;
  int j = blockIdx.x * 4 + wid;
  if (j >= n) return;
  float dj = dinv[j];
  float hj = h[(size_t)j * 64 + lane];
  int e0 = colp[j], e1 = colp[j + 1];
  float s = 0.0f;
  int e = e0;
  for (; e + 4 <= e1; e += 4) {
    int2 m0 = csr[e], m1 = csr[e + 1], m2 = csr[e + 2], m3 = csr[e + 3];
    float f0 = h[(size_t)m0.x * 64 + lane];
    float f1 = h[(size_t)m1.x * 64 + lane];
    float f2 = h[(size_t)m2.x * 64 + lane];
    float f3 = h[(size_t)m3.x * 64 + lane];
    s = fmaf(__int_as_float(m0.y), f0, s);
    s = fmaf(__int_as_float(m1.y), f1, s);
    s = fmaf(__int_as_float(m2.y), f2, s);
    s = fmaf(__int_as_float(m3.y), f3, s);
  }
  for (; e < e1; ++e) {
    int2 m = csr[e];
    s = fmaf(__int_as_float(m.y), h[(size_t)m.x * 64 + lane], s);
  }
  float acc = bias[lane] + dj * fmaf(dj, hj, s);
  out[(size_t)j * 64 + lane] = fmaxf(acc, 0.0f);
}

// ---------------- pool + classifier ----------------

__global__ __launch_bounds__(256) void pool_kernel(const float* __restrict__ x,
                                                   const int* __restrict__ batch,
                                                   float* __restrict__ pooled, int n) {
  __shared__ float red[4][64];
  __shared__ int range_s[2];
  int gph = blockIdx.x;
  int tid = threadIdx.x, wid = tid >> 6, lane = tid & 63;
  if (tid < 2) {
    int target = gph + tid;
    int lo = 0, hi = n;
    while (lo < hi) { int m = (lo + hi) >> 1; if (batch[m] < target) lo = m + 1; else hi = m; }
    range_s[tid] = lo;
  }
  __syncthreads();
  int lo = range_s[0], hi = range_s[1];
  float acc = 0.0f;
  for (int i = lo + wid; i < hi; i += 4) acc += x[(size_t)i * 64 + lane];
  red[wid][lane] = acc;
  __syncthreads();
  if (tid < 64) {
    float sum = red[0][lane] + red[1][lane] + red[2][lane] + red[3][lane];
    float cntf = (float)(hi - lo);
    pooled[gph * 64 + lane] = sum / fmaxf(cntf, 1.0f);
  }
}

__global__ void cls_kernel(const float* __restrict__ pooled, const float* __restrict__ cw,
                           const float* __restrict__ cb, float* __restrict__ out) {
  int t = threadIdx.x;  // 256 threads = 128 graphs x 2 classes
  int gph = t >> 1, c = t & 1;
  float acc = cb[c];
  #pragma unroll 8
  for (int k = 0; k < 64; ++k) acc = fmaf(pooled[gph * 64 + k], cw[k * 2 + c], acc);
  out[gph * 2 + c] = acc;
}

// ---------------- launch ----------------

extern "C" void kernel_launch(void* const* d_in, const int* in_sizes, int n_in,
                              void* d_out, int out_size, void* d_ws, size_t ws_size,
                              hipStream_t stream) {
  const int*   x_names  = (const int*)  d_in[0];
  const int*   x_types  = (const int*)  d_in[1];
  const float* behav    = (const float*)d_in[2];
  const int*   ei       = (const int*)  d_in[3];
  const float* ew       = (const float*)d_in[4];
  const int*   batch    = (const int*)  d_in[5];
  const float* llm      = (const float*)d_in[6];
  const float* name_emb = (const float*)d_in[7];
  const float* type_emb = (const float*)d_in[8];
  const float* pw       = (const float*)d_in[9];
  const float* pb       = (const float*)d_in[10];
  const float* w1       = (const float*)d_in[11];
  const float* b1       = (const float*)d_in[12];
  const float* w2       = (const float*)d_in[13];
  const float* b2       = (const float*)d_in[14];
  const float* cw       = (const float*)d_in[15];
  const float* cb       = (const float*)d_in[16];

  const int N = in_sizes[0];
  const int E = in_sizes[4];
  const int nb = (N + 255) / 256;
  const int eb = (E + 255) / 256;
  const int tiles = (N + BM - 1) / BM;

  char* p = (char*)d_ws;
  auto alloc = [&](size_t bytes) -> void* {
    void* r = (void*)p; p += (bytes + 255) & ~(size_t)255; return r;
  };
  float* dinv   = (float*)alloc((size_t)N * 4);
  int*   cnt    = (int*)  alloc((size_t)N * 4);
  int*   colp   = (int*)  alloc((size_t)(N + 1) * 4);
  int*   fillp  = (int*)  alloc((size_t)N * 4);
  int2*  csr    = (int2*) alloc((size_t)E * 8);
  int*   bsum   = (int*)  alloc((size_t)(nb + 1) * 4);
  float* Wf     = (float*)alloc((size_t)768 * 64 * 4);
  float* biasf  = (float*)alloc((size_t)64 * 4);
  float* bufX   = (float*)alloc((size_t)N * 64 * 4);
  float* bufY   = (float*)alloc((size_t)N * 64 * 4);
  float* pooled = (float*)alloc((size_t)128 * 64 * 4);
  (void)ws_size; (void)n_in; (void)out_size;

  prep_kernel<<<(768 * 64 + 64 + 255) / 256, 256, 0, stream>>>(pw, pb, w1, Wf, biasf);
  zero_kernel<<<nb, 256, 0, stream>>>(cnt, N);
  cnt_kernel<<<eb, 256, 0, stream>>>(ei, cnt, E);
  scan_blk<<<nb, 256, 0, stream>>>(cnt, colp, bsum, N);
  scan_top<<<1, 512, 0, stream>>>(bsum, colp, nb, N);
  scan_add<<<nb, 256, 0, stream>>>(colp, fillp, bsum, N);
  fill_kernel<<<eb, 256, 0, stream>>>(ei, ew, fillp, csr, E);
  degsum_kernel<<<nb, 256, 0, stream>>>(colp, csr, dinv, N);
  wfix_kernel<<<eb, 256, 0, stream>>>(csr, dinv, E);

  gemm1_kernel<<<tiles, 256, 0, stream>>>(llm, Wf, x_names, x_types, behav,
                                          name_emb, type_emb, w1, biasf, bufX, N);
  agg_kernel<<<(N + 3) / 4, 256, 0, stream>>>(bufX, colp, csr, dinv, b1, bufY, N);
  gemm2_kernel<<<tiles, 256, 0, stream>>>(bufY, w2, bufX, N);
  agg_kernel<<<(N + 3) / 4, 256, 0, stream>>>(bufX, colp, csr, dinv, b2, bufY, N);
  pool_kernel<<<128, 256, 0, stream>>>(bufY, batch, pooled, N);
  cls_kernel<<<1, 256, 0, stream>>>(pooled, cw, cb, (float*)d_out);
}

// Round 3
// 587.483 us; speedup vs baseline: 1.6254x; 1.1181x over previous
//
#include <hip/hip_runtime.h>
#include <cstdint>
#include <cstddef>

typedef __attribute__((ext_vector_type(8))) short bf16x8;
typedef __attribute__((ext_vector_type(4))) float f32x4;

// ---------------- bf16 split helpers ----------------

__device__ __forceinline__ unsigned bf_rne(float x) {
  unsigned u = __float_as_uint(x);
  return (u + 0x7FFFu + ((u >> 16) & 1u)) >> 16;
}

__device__ __forceinline__ void split1(float x, short& hi, short& lo) {
  unsigned hb = bf_rne(x);
  hi = (short)hb;
  float fh = __uint_as_float(hb << 16);
  lo = (short)bf_rne(x - fh);
}

// fragment split: elems 0-3 <- p, elems 4-7 <- q
__device__ __forceinline__ void split8(const float4& p, const float4& q, bf16x8& h, bf16x8& l) {
  short hh, ll;
  split1(p.x, hh, ll); h[0] = hh; l[0] = ll;
  split1(p.y, hh, ll); h[1] = hh; l[1] = ll;
  split1(p.z, hh, ll); h[2] = hh; l[2] = ll;
  split1(p.w, hh, ll); h[3] = hh; l[3] = ll;
  split1(q.x, hh, ll); h[4] = hh; l[4] = ll;
  split1(q.y, hh, ll); h[5] = hh; l[5] = ll;
  split1(q.z, hh, ll); h[6] = hh; l[6] = ll;
  split1(q.w, hh, ll); h[7] = hh; l[7] = ll;
}

// ---------------- prep: build fragment-ordered split-bf16 weights ----------------
// Wall (896 x 64): rows 0..767 = llm_proj_w @ conv1_w[80:112] (Wf), 768..831 = W1[0:64],
// 832..847 = W1[64:80] (type), 848..863 = W1[112:128] (behav lo), 864..879 = W1[128:144] (behav hi),
// 880..895 = 0.  Stored as B-fragments: [(chunk*4+g)*64 + col][8], j<4 <-> k=g*4+j, j>=4 <-> k=16+g*4+j-4.

__global__ void prep1_kernel(const float* __restrict__ pw, const float* __restrict__ pb,
                             const float* __restrict__ w1,
                             short* __restrict__ Bh, short* __restrict__ Bl,
                             float* __restrict__ biasf) {
  int idx = blockIdx.x * 256 + threadIdx.x;
  if (idx < 896 * 64) {
    int gk = idx >> 6, col = idx & 63;
    float val;
    if (gk < 768) {
      float acc = 0.0f;
      #pragma unroll 8
      for (int m = 0; m < 32; ++m) acc = fmaf(pw[gk * 32 + m], w1[(80 + m) * 64 + col], acc);
      val = acc;
    } else if (gk < 832) val = w1[(gk - 768) * 64 + col];
    else if (gk < 848)   val = w1[(64 + gk - 832) * 64 + col];
    else if (gk < 864)   val = w1[(112 + gk - 848) * 64 + col];
    else if (gk < 880)   val = w1[(128 + gk - 864) * 64 + col];
    else                 val = 0.0f;
    int chunk = gk >> 5, k = gk & 31;
    int g, j;
    if (k < 16) { g = k >> 2; j = k & 3; } else { int k2 = k - 16; g = k2 >> 2; j = 4 + (k2 & 3); }
    size_t o = ((size_t)(chunk * 4 + g) * 64 + col) * 8 + j;
    short hh, ll; split1(val, hh, ll);
    Bh[o] = hh; Bl[o] = ll;
  } else if (idx < 896 * 64 + 64) {
    int col = idx - 896 * 64;
    float acc = 0.0f;
    for (int m = 0; m < 32; ++m) acc = fmaf(pb[m], w1[(80 + m) * 64 + col], acc);
    biasf[col] = acc;
  }
}

__global__ void prep2_kernel(const float* __restrict__ w2,
                             short* __restrict__ B2h, short* __restrict__ B2l) {
  int idx = blockIdx.x * 256 + threadIdx.x;
  if (idx >= 64 * 64) return;
  int gk = idx >> 6, col = idx & 63;
  float val = w2[gk * 64 + col];
  int chunk = gk >> 5, k = gk & 31;
  int g, j;
  if (k < 16) { g = k >> 2; j = k & 3; } else { int k2 = k - 16; g = k2 >> 2; j = 4 + (k2 & 3); }
  size_t o = ((size_t)(chunk * 4 + g) * 64 + col) * 8 + j;
  short hh, ll; split1(val, hh, ll);
  B2h[o] = hh; B2l[o] = ll;
}

// ---------------- CSR build ----------------

__global__ void zero_kernel(int* __restrict__ cnt, int n) {
  int i = blockIdx.x * 256 + threadIdx.x;
  if (i < n) cnt[i] = 0;
}

__global__ void cnt_kernel(const int* __restrict__ ei, int* __restrict__ cnt, int E) {
  int e = blockIdx.x * 256 + threadIdx.x;
  if (e < E) atomicAdd(&cnt[ei[E + e]], 1);
}

__global__ __launch_bounds__(256) void scan_blk(const int* __restrict__ cnt,
                                                int* __restrict__ colp,
                                                int* __restrict__ bsum, int n) {
  __shared__ int ws[4];
  int t = threadIdx.x, lane = t & 63, w = t >> 6;
  int i = blockIdx.x * 256 + t;
  int v = (i < n) ? cnt[i] : 0;
  int x = v;
  #pragma unroll
  for (int off = 1; off < 64; off <<= 1) { int y = __shfl_up(x, off); if (lane >= off) x += y; }
  if (lane == 63) ws[w] = x;
  __syncthreads();
  if (t == 0) {
    int s = 0;
    #pragma unroll
    for (int k = 0; k < 4; ++k) { int tmp = ws[k]; ws[k] = s; s += tmp; }
    bsum[blockIdx.x] = s;
  }
  __syncthreads();
  if (i < n) colp[i] = ws[w] + x - v;
}

__global__ __launch_bounds__(512) void scan_top(int* __restrict__ bsum,
                                                int* __restrict__ colp, int nb, int n) {
  __shared__ int ws[8];
  int t = threadIdx.x, lane = t & 63, w = t >> 6;
  int v = (t < nb) ? bsum[t] : 0;
  int x = v;
  #pragma unroll
  for (int off = 1; off < 64; off <<= 1) { int y = __shfl_up(x, off); if (lane >= off) x += y; }
  if (lane == 63) ws[w] = x;
  __syncthreads();
  if (t == 0) {
    int s = 0;
    #pragma unroll
    for (int k = 0; k < 8; ++k) { int tmp = ws[k]; ws[k] = s; s += tmp; }
  }
  __syncthreads();
  int excl = ws[w] + x - v;
  if (t < nb) bsum[t] = excl;
  if (t == nb - 1) colp[n] = excl + v;
}

__global__ void scan_add(int* __restrict__ colp, int* __restrict__ fillp,
                         const int* __restrict__ bsum, int n) {
  int i = blockIdx.x * 256 + threadIdx.x;
  if (i < n) {
    int c = colp[i] + bsum[blockIdx.x];
    colp[i] = c;
    fillp[i] = c;
  }
}

__global__ void fill_kernel(const int* __restrict__ ei, const float* __restrict__ ew,
                            int* __restrict__ fillp, int2* __restrict__ csr, int E) {
  int e = blockIdx.x * 256 + threadIdx.x;
  if (e >= E) return;
  int row = ei[e], col = ei[E + e];
  int pos = atomicAdd(&fillp[col], 1);
  csr[pos] = make_int2(row, __float_as_int(ew[e]));
}

__global__ void degsum_kernel(const int* __restrict__ colp, const int2* __restrict__ csr,
                              float* __restrict__ dinv, int n) {
  int j = blockIdx.x * 256 + threadIdx.x;
  if (j >= n) return;
  int e0 = colp[j], e1 = colp[j + 1];
  float s = 1.0f;
  for (int e = e0; e < e1; ++e) s += __int_as_float(csr[e].y);
  dinv[j] = rsqrtf(s);
}

__global__ void wfix_kernel(int2* __restrict__ csr, const float* __restrict__ dinv, int E) {
  int i = blockIdx.x * 256 + threadIdx.x;
  if (i >= E) return;
  int2 m = csr[i];
  csr[i] = make_int2(m.x, __float_as_int(__int_as_float(m.y) * dinv[m.x]));
}

// ---------------- gemm1: barrier-free streaming MFMA ----------------
// One wave owns 32 rows x 64 cols. A fragments loaded directly from global
// (llm / name_emb / type_emb / behav per chunk), B fragments from prep'd arrays.

__device__ __forceinline__ void loadA1(int c, int arow, bool inb, int nm, int tp, int g,
                                       const float* __restrict__ llm,
                                       const float* __restrict__ nemb,
                                       const float* __restrict__ temb,
                                       const float* __restrict__ beh,
                                       float4& lo, float4& hi) {
  const float4 z = make_float4(0.f, 0.f, 0.f, 0.f);
  if (c < 24) {
    const float* p = llm + (size_t)arow * 768 + c * 32 + g * 4;
    lo = inb ? *(const float4*)p : z;
    hi = inb ? *(const float4*)(p + 16) : z;
  } else if (c < 26) {
    const float* p = nemb + (size_t)nm * 64 + (c - 24) * 32 + g * 4;
    lo = *(const float4*)p;        // nm==0 for out-of-range rows: valid, store-guarded
    hi = *(const float4*)(p + 16);
  } else if (c == 26) {
    lo = *(const float4*)(temb + (size_t)tp * 16 + g * 4);
    hi = inb ? *(const float4*)(beh + (size_t)arow * 32 + g * 4) : z;
  } else {
    lo = inb ? *(const float4*)(beh + (size_t)arow * 32 + 16 + g * 4) : z;
    hi = z;
  }
}

__global__ __launch_bounds__(256, 4) void gemm1_kernel(
    const float* __restrict__ llm, const short* __restrict__ Bh, const short* __restrict__ Bl,
    const int* __restrict__ names, const int* __restrict__ types,
    const float* __restrict__ beh, const float* __restrict__ nemb,
    const float* __restrict__ temb, const float* __restrict__ biasf,
    float* __restrict__ out, int n)
{
  int w = blockIdx.x * 4 + (threadIdx.x >> 6);
  int nw = (n + 31) >> 5;
  if (w >= nw) return;
  int lane = threadIdx.x & 63;
  int g = lane >> 4, r16 = lane & 15;
  int base = w * 32;

  int arow0 = base + r16, arow1 = base + 16 + r16;
  bool inb0 = arow0 < n, inb1 = arow1 < n;
  int nm0 = inb0 ? names[arow0] : 0;
  int nm1 = inb1 ? names[arow1] : 0;
  int tp0 = inb0 ? types[arow0] : 0;
  int tp1 = inb1 ? types[arow1] : 0;

  f32x4 acc[2][4];
  #pragma unroll
  for (int i = 0; i < 2; ++i)
    #pragma unroll
    for (int j = 0; j < 4; ++j) { acc[i][j][0] = 0.f; acc[i][j][1] = 0.f; acc[i][j][2] = 0.f; acc[i][j][3] = 0.f; }

  float4 aLo0, aHi0, aLo1, aHi1, nLo0, nHi0, nLo1, nHi1;
  loadA1(0, arow0, inb0, nm0, tp0, g, llm, nemb, temb, beh, aLo0, aHi0);
  loadA1(0, arow1, inb1, nm1, tp1, g, llm, nemb, temb, beh, aLo1, aHi1);

  #pragma unroll 1
  for (int c = 0; c < 28; ++c) {
    bf16x8 bh[4], bl[4];
    #pragma unroll
    for (int ct = 0; ct < 4; ++ct) {
      size_t o = ((size_t)(c * 4 + g) * 64 + ct * 16 + r16) * 8;
      bh[ct] = *(const bf16x8*)(Bh + o);
      bl[ct] = *(const bf16x8*)(Bl + o);
    }
    if (c < 27) {
      loadA1(c + 1, arow0, inb0, nm0, tp0, g, llm, nemb, temb, beh, nLo0, nHi0);
      loadA1(c + 1, arow1, inb1, nm1, tp1, g, llm, nemb, temb, beh, nLo1, nHi1);
    }
    bf16x8 ah, al;
    split8(aLo0, aHi0, ah, al);
    #pragma unroll
    for (int ct = 0; ct < 4; ++ct) {
      acc[0][ct] = __builtin_amdgcn_mfma_f32_16x16x32_bf16(ah, bh[ct], acc[0][ct], 0, 0, 0);
      acc[0][ct] = __builtin_amdgcn_mfma_f32_16x16x32_bf16(ah, bl[ct], acc[0][ct], 0, 0, 0);
      acc[0][ct] = __builtin_amdgcn_mfma_f32_16x16x32_bf16(al, bh[ct], acc[0][ct], 0, 0, 0);
    }
    split8(aLo1, aHi1, ah, al);
    #pragma unroll
    for (int ct = 0; ct < 4; ++ct) {
      acc[1][ct] = __builtin_amdgcn_mfma_f32_16x16x32_bf16(ah, bh[ct], acc[1][ct], 0, 0, 0);
      acc[1][ct] = __builtin_amdgcn_mfma_f32_16x16x32_bf16(ah, bl[ct], acc[1][ct], 0, 0, 0);
      acc[1][ct] = __builtin_amdgcn_mfma_f32_16x16x32_bf16(al, bh[ct], acc[1][ct], 0, 0, 0);
    }
    aLo0 = nLo0; aHi0 = nHi0; aLo1 = nLo1; aHi1 = nHi1;
  }

  // C/D: col = lane&15 (+16*ct), row = (lane>>4)*4 + reg (+16*rt)
  #pragma unroll
  for (int ct = 0; ct < 4; ++ct) {
    int col = ct * 16 + r16;
    float bf = biasf[col];
    #pragma unroll
    for (int rr = 0; rr < 4; ++rr) {
      int node0 = base + g * 4 + rr;
      if (node0 < n) out[(size_t)node0 * 64 + col] = acc[0][ct][rr] + bf;
      int node1 = base + 16 + g * 4 + rr;
      if (node1 < n) out[(size_t)node1 * 64 + col] = acc[1][ct][rr] + bf;
    }
  }
}

// ---------------- gemm2: h @ W2, same streaming structure, K=64 ----------------

__global__ __launch_bounds__(256, 4) void gemm2_kernel(
    const float* __restrict__ h, const short* __restrict__ B2h, const short* __restrict__ B2l,
    float* __restrict__ out, int n)
{
  int w = blockIdx.x * 4 + (threadIdx.x >> 6);
  int nw = (n + 31) >> 5;
  if (w >= nw) return;
  int lane = threadIdx.x & 63;
  int g = lane >> 4, r16 = lane & 15;
  int base = w * 32;
  int arow0 = base + r16, arow1 = base + 16 + r16;
  bool inb0 = arow0 < n, inb1 = arow1 < n;
  const float4 z = make_float4(0.f, 0.f, 0.f, 0.f);

  f32x4 acc[2][4];
  #pragma unroll
  for (int i = 0; i < 2; ++i)
    #pragma unroll
    for (int j = 0; j < 4; ++j) { acc[i][j][0] = 0.f; acc[i][j][1] = 0.f; acc[i][j][2] = 0.f; acc[i][j][3] = 0.f; }

  #pragma unroll
  for (int c = 0; c < 2; ++c) {
    bf16x8 bh[4], bl[4];
    #pragma unroll
    for (int ct = 0; ct < 4; ++ct) {
      size_t o = ((size_t)(c * 4 + g) * 64 + ct * 16 + r16) * 8;
      bh[ct] = *(const bf16x8*)(B2h + o);
      bl[ct] = *(const bf16x8*)(B2l + o);
    }
    const float* p0 = h + (size_t)arow0 * 64 + c * 32 + g * 4;
    const float* p1 = h + (size_t)arow1 * 64 + c * 32 + g * 4;
    float4 lo0 = inb0 ? *(const float4*)p0 : z;
    float4 hi0 = inb0 ? *(const float4*)(p0 + 16) : z;
    float4 lo1 = inb1 ? *(const float4*)p1 : z;
    float4 hi1 = inb1 ? *(const float4*)(p1 + 16) : z;
    bf16x8 ah, al;
    split8(lo0, hi0, ah, al);
    #pragma unroll
    for (int ct = 0; ct < 4; ++ct) {
      acc[0][ct] = __builtin_amdgcn_mfma_f32_16x16x32_bf16(ah, bh[ct], acc[0][ct], 0, 0, 0);
      acc[0][ct] = __builtin_amdgcn_mfma_f32_16x16x32_bf16(ah, bl[ct], acc[0][ct], 0, 0, 0);
      acc[0][ct] = __builtin_amdgcn_mfma_f32_16x16x32_bf16(al, bh[ct], acc[0][ct], 0, 0, 0);
    }
    split8(lo1, hi1, ah, al);
    #pragma unroll
    for (int ct = 0; ct < 4; ++ct) {
      acc[1][ct] = __builtin_amdgcn_mfma_f32_16x16x32_bf16(ah, bh[ct], acc[1][ct], 0, 0, 0);
      acc[1][ct] = __builtin_amdgcn_mfma_f32_16x16x32_bf16(ah, bl[ct], acc[1][ct], 0, 0, 0);
      acc[1][ct] = __builtin_amdgcn_mfma_f32_16x16x32_bf16(al, bh[ct], acc[1][ct], 0, 0, 0);
    }
  }

  #pragma unroll
  for (int ct = 0; ct < 4; ++ct) {
    int col = ct * 16 + r16;
    #pragma unroll
    for (int rr = 0; rr < 4; ++rr) {
      int node0 = base + g * 4 + rr;
      if (node0 < n) out[(size_t)node0 * 64 + col] = acc[0][ct][rr];
      int node1 = base + 16 + g * 4 + rr;
      if (node1 < n) out[(size_t)node1 * 64 + col] = acc[1][ct][rr];
    }
  }
}

// ---------------- aggregation ----------------

__global__ __launch_bounds__(256) void agg_kernel(
    const float* __restrict__ h, const int* __restrict__ colp,
    const int2* __restrict__ csr, const float* __restrict__ dinv,
    const float* __restrict__ bias, float* __restrict__ out, int n)
{
  int wid = threadIdx.x >> 6, lane = threadIdx.x & 63;
  int j = blockIdx.x * 4 + wid;
  if (j >= n) return;
  float dj = dinv[j];
  float hj = h[(size_t)j * 64 + lane];
  int e0 = colp[j], e1 = colp[j + 1];
  float s = 0.0f;
  int e = e0;
  for (; e + 4 <= e1; e += 4) {
    int2 m0 = csr[e], m1 = csr[e + 1], m2 = csr[e + 2], m3 = csr[e + 3];
    float f0 = h[(size_t)m0.x * 64 + lane];
    float f1 = h[(size_t)m1.x * 64 + lane];
    float f2 = h[(size_t)m2.x * 64 + lane];
    float f3 = h[(size_t)m3.x * 64 + lane];
    s = fmaf(__int_as_float(m0.y), f0, s);
    s = fmaf(__int_as_float(m1.y), f1, s);
    s = fmaf(__int_as_float(m2.y), f2, s);
    s = fmaf(__int_as_float(m3.y), f3, s);
  }
  for (; e < e1; ++e) {
    int2 m = csr[e];
    s = fmaf(__int_as_float(m.y), h[(size_t)m.x * 64 + lane], s);
  }
  float acc = bias[lane] + dj * fmaf(dj, hj, s);
  out[(size_t)j * 64 + lane] = fmaxf(acc, 0.0f);
}

// ---------------- pool + classifier ----------------

__global__ __launch_bounds__(256) void pool_kernel(const float* __restrict__ x,
                                                   const int* __restrict__ batch,
                                                   float* __restrict__ pooled, int n) {
  __shared__ float red[4][64];
  __shared__ int range_s[2];
  int gph = blockIdx.x;
  int tid = threadIdx.x, wid = tid >> 6, lane = tid & 63;
  if (tid < 2) {
    int target = gph + tid;
    int lo = 0, hi = n;
    while (lo < hi) { int m = (lo + hi) >> 1; if (batch[m] < target) lo = m + 1; else hi = m; }
    range_s[tid] = lo;
  }
  __syncthreads();
  int lo = range_s[0], hi = range_s[1];
  float acc = 0.0f;
  for (int i = lo + wid; i < hi; i += 4) acc += x[(size_t)i * 64 + lane];
  red[wid][lane] = acc;
  __syncthreads();
  if (tid < 64) {
    float sum = red[0][lane] + red[1][lane] + red[2][lane] + red[3][lane];
    float cntf = (float)(hi - lo);
    pooled[gph * 64 + lane] = sum / fmaxf(cntf, 1.0f);
  }
}

__global__ void cls_kernel(const float* __restrict__ pooled, const float* __restrict__ cw,
                           const float* __restrict__ cb, float* __restrict__ out) {
  int t = threadIdx.x;  // 256 threads = 128 graphs x 2 classes
  int gph = t >> 1, c = t & 1;
  float acc = cb[c];
  #pragma unroll 8
  for (int k = 0; k < 64; ++k) acc = fmaf(pooled[gph * 64 + k], cw[k * 2 + c], acc);
  out[gph * 2 + c] = acc;
}

// ---------------- launch ----------------

extern "C" void kernel_launch(void* const* d_in, const int* in_sizes, int n_in,
                              void* d_out, int out_size, void* d_ws, size_t ws_size,
                              hipStream_t stream) {
  const int*   x_names  = (const int*)  d_in[0];
  const int*   x_types  = (const int*)  d_in[1];
  const float* behav    = (const float*)d_in[2];
  const int*   ei       = (const int*)  d_in[3];
  const float* ew       = (const float*)d_in[4];
  const int*   batch    = (const int*)  d_in[5];
  const float* llm      = (const float*)d_in[6];
  const float* name_emb = (const float*)d_in[7];
  const float* type_emb = (const float*)d_in[8];
  const float* pw       = (const float*)d_in[9];
  const float* pb       = (const float*)d_in[10];
  const float* w1       = (const float*)d_in[11];
  const float* b1       = (const float*)d_in[12];
  const float* w2       = (const float*)d_in[13];
  const float* b2       = (const float*)d_in[14];
  const float* cw       = (const float*)d_in[15];
  const float* cb       = (const float*)d_in[16];

  const int N = in_sizes[0];
  const int E = in_sizes[4];
  const int nb = (N + 255) / 256;
  const int eb = (E + 255) / 256;
  const int nwaves = (N + 31) / 32;
  const int gblocks = (nwaves + 3) / 4;

  char* p = (char*)d_ws;
  auto alloc = [&](size_t bytes) -> void* {
    void* r = (void*)p; p += (bytes + 255) & ~(size_t)255; return r;
  };
  float* dinv   = (float*)alloc((size_t)N * 4);
  int*   cnt    = (int*)  alloc((size_t)N * 4);
  int*   colp   = (int*)  alloc((size_t)(N + 1) * 4);
  int*   fillp  = (int*)  alloc((size_t)N * 4);
  int2*  csr    = (int2*) alloc((size_t)E * 8);
  int*   bsum   = (int*)  alloc((size_t)(nb + 1) * 4);
  short* Bh     = (short*)alloc((size_t)896 * 64 * 2);
  short* Bl     = (short*)alloc((size_t)896 * 64 * 2);
  short* B2h    = (short*)alloc((size_t)64 * 64 * 2);
  short* B2l    = (short*)alloc((size_t)64 * 64 * 2);
  float* biasf  = (float*)alloc((size_t)64 * 4);
  float* bufX   = (float*)alloc((size_t)N * 64 * 4);
  float* bufY   = (float*)alloc((size_t)N * 64 * 4);
  float* pooled = (float*)alloc((size_t)128 * 64 * 4);
  (void)ws_size; (void)n_in; (void)out_size;

  prep1_kernel<<<(896 * 64 + 64 + 255) / 256, 256, 0, stream>>>(pw, pb, w1, Bh, Bl, biasf);
  prep2_kernel<<<16, 256, 0, stream>>>(w2, B2h, B2l);
  zero_kernel<<<nb, 256, 0, stream>>>(cnt, N);
  cnt_kernel<<<eb, 256, 0, stream>>>(ei, cnt, E);
  scan_blk<<<nb, 256, 0, stream>>>(cnt, colp, bsum, N);
  scan_top<<<1, 512, 0, stream>>>(bsum, colp, nb, N);
  scan_add<<<nb, 256, 0, stream>>>(colp, fillp, bsum, N);
  fill_kernel<<<eb, 256, 0, stream>>>(ei, ew, fillp, csr, E);
  degsum_kernel<<<nb, 256, 0, stream>>>(colp, csr, dinv, N);
  wfix_kernel<<<eb, 256, 0, stream>>>(csr, dinv, E);

  gemm1_kernel<<<gblocks, 256, 0, stream>>>(llm, Bh, Bl, x_names, x_types, behav,
                                            name_emb, type_emb, biasf, bufX, N);
  agg_kernel<<<(N + 3) / 4, 256, 0, stream>>>(bufX, colp, csr, dinv, b1, bufY, N);
  gemm2_kernel<<<gblocks, 256, 0, stream>>>(bufY, B2h, B2l, bufX, N);
  agg_kernel<<<(N + 3) / 4, 256, 0, stream>>>(bufX, colp, csr, dinv, b2, bufY, N);
  pool_kernel<<<128, 256, 0, stream>>>(bufY, batch, pooled, N);
  cls_kernel<<<1, 256, 0, stream>>>(pooled, cw, cb, (float*)d_out);
}

// Round 4
// 548.182 us; speedup vs baseline: 1.7419x; 1.0717x over previous
//
#include <hip/hip_runtime.h>
#include <cstdint>
#include <cstddef>

typedef __attribute__((ext_vector_type(8))) short bf16x8;
typedef __attribute__((ext_vector_type(4))) float f32x4;

// ---------------- bf16 split helpers ----------------

__device__ __forceinline__ unsigned bf_rne(float x) {
  unsigned u = __float_as_uint(x);
  return (u + 0x7FFFu + ((u >> 16) & 1u)) >> 16;
}

__device__ __forceinline__ void split1(float x, short& hi, short& lo) {
  unsigned hb = bf_rne(x);
  hi = (short)hb;
  float fh = __uint_as_float(hb << 16);
  lo = (short)bf_rne(x - fh);
}

// fragment split: elems 0-3 <- p, elems 4-7 <- q
__device__ __forceinline__ void split8(const float4& p, const float4& q, bf16x8& h, bf16x8& l) {
  short hh, ll;
  split1(p.x, hh, ll); h[0] = hh; l[0] = ll;
  split1(p.y, hh, ll); h[1] = hh; l[1] = ll;
  split1(p.z, hh, ll); h[2] = hh; l[2] = ll;
  split1(p.w, hh, ll); h[3] = hh; l[3] = ll;
  split1(q.x, hh, ll); h[4] = hh; l[4] = ll;
  split1(q.y, hh, ll); h[5] = hh; l[5] = ll;
  split1(q.z, hh, ll); h[6] = hh; l[6] = ll;
  split1(q.w, hh, ll); h[7] = hh; l[7] = ll;
}

// ---------------- prep: build fragment-ordered split-bf16 weights ----------------

__global__ void prep1_kernel(const float* __restrict__ pw, const float* __restrict__ pb,
                             const float* __restrict__ w1,
                             short* __restrict__ Bh, short* __restrict__ Bl,
                             float* __restrict__ biasf) {
  int idx = blockIdx.x * 256 + threadIdx.x;
  if (idx < 896 * 64) {
    int gk = idx >> 6, col = idx & 63;
    float val;
    if (gk < 768) {
      float acc = 0.0f;
      #pragma unroll 8
      for (int m = 0; m < 32; ++m) acc = fmaf(pw[gk * 32 + m], w1[(80 + m) * 64 + col], acc);
      val = acc;
    } else if (gk < 832) val = w1[(gk - 768) * 64 + col];
    else if (gk < 848)   val = w1[(64 + gk - 832) * 64 + col];
    else if (gk < 864)   val = w1[(112 + gk - 848) * 64 + col];
    else if (gk < 880)   val = w1[(128 + gk - 864) * 64 + col];
    else                 val = 0.0f;
    int chunk = gk >> 5, k = gk & 31;
    int g, j;
    if (k < 16) { g = k >> 2; j = k & 3; } else { int k2 = k - 16; g = k2 >> 2; j = 4 + (k2 & 3); }
    size_t o = ((size_t)(chunk * 4 + g) * 64 + col) * 8 + j;
    short hh, ll; split1(val, hh, ll);
    Bh[o] = hh; Bl[o] = ll;
  } else if (idx < 896 * 64 + 64) {
    int col = idx - 896 * 64;
    float acc = 0.0f;
    for (int m = 0; m < 32; ++m) acc = fmaf(pb[m], w1[(80 + m) * 64 + col], acc);
    biasf[col] = acc;
  }
}

__global__ void prep2_kernel(const float* __restrict__ w2,
                             short* __restrict__ B2h, short* __restrict__ B2l) {
  int idx = blockIdx.x * 256 + threadIdx.x;
  if (idx >= 64 * 64) return;
  int gk = idx >> 6, col = idx & 63;
  float val = w2[gk * 64 + col];
  int chunk = gk >> 5, k = gk & 31;
  int g, j;
  if (k < 16) { g = k >> 2; j = k & 3; } else { int k2 = k - 16; g = k2 >> 2; j = 4 + (k2 & 3); }
  size_t o = ((size_t)(chunk * 4 + g) * 64 + col) * 8 + j;
  short hh, ll; split1(val, hh, ll);
  B2h[o] = hh; B2l[o] = ll;
}

// ---------------- CSR build ----------------

__global__ void cnt_kernel(const int* __restrict__ ei, int* __restrict__ cnt, int E) {
  int e = blockIdx.x * 256 + threadIdx.x;
  if (e < E) atomicAdd(&cnt[ei[E + e]], 1);
}

__global__ __launch_bounds__(256) void scan_blk(const int* __restrict__ cnt,
                                                int* __restrict__ colp,
                                                int* __restrict__ bsum, int n) {
  __shared__ int ws[4];
  int t = threadIdx.x, lane = t & 63, w = t >> 6;
  int i = blockIdx.x * 256 + t;
  int v = (i < n) ? cnt[i] : 0;
  int x = v;
  #pragma unroll
  for (int off = 1; off < 64; off <<= 1) { int y = __shfl_up(x, off); if (lane >= off) x += y; }
  if (lane == 63) ws[w] = x;
  __syncthreads();
  if (t == 0) {
    int s = 0;
    #pragma unroll
    for (int k = 0; k < 4; ++k) { int tmp = ws[k]; ws[k] = s; s += tmp; }
    bsum[blockIdx.x] = s;
  }
  __syncthreads();
  if (i < n) colp[i] = ws[w] + x - v;
}

__global__ __launch_bounds__(512) void scan_top(int* __restrict__ bsum,
                                                int* __restrict__ colp, int nb, int n) {
  __shared__ int ws[8];
  int t = threadIdx.x, lane = t & 63, w = t >> 6;
  int v = (t < nb) ? bsum[t] : 0;
  int x = v;
  #pragma unroll
  for (int off = 1; off < 64; off <<= 1) { int y = __shfl_up(x, off); if (lane >= off) x += y; }
  if (lane == 63) ws[w] = x;
  __syncthreads();
  if (t == 0) {
    int s = 0;
    #pragma unroll
    for (int k = 0; k < 8; ++k) { int tmp = ws[k]; ws[k] = s; s += tmp; }
  }
  __syncthreads();
  int excl = ws[w] + x - v;
  if (t < nb) bsum[t] = excl;
  if (t == nb - 1) colp[n] = excl + v;
}

__global__ void scan_add(int* __restrict__ colp, int* __restrict__ fillp,
                         const int* __restrict__ bsum, int n) {
  int i = blockIdx.x * 256 + threadIdx.x;
  if (i < n) {
    int c = colp[i] + bsum[blockIdx.x];
    colp[i] = c;
    fillp[i] = c;
  }
}

__global__ void fill_kernel(const int* __restrict__ ei, const float* __restrict__ ew,
                            int* __restrict__ fillp, int2* __restrict__ csr, int E) {
  int e = blockIdx.x * 256 + threadIdx.x;
  if (e >= E) return;
  int row = ei[e], col = ei[E + e];
  int pos = atomicAdd(&fillp[col], 1);
  csr[pos] = make_int2(row, __float_as_int(ew[e]));
}

__global__ void degsum_kernel(const int* __restrict__ colp, const int2* __restrict__ csr,
                              float* __restrict__ dinv, int n) {
  int j = blockIdx.x * 256 + threadIdx.x;
  if (j >= n) return;
  int e0 = colp[j], e1 = colp[j + 1];
  float s = 1.0f;
  for (int e = e0; e < e1; ++e) s += __int_as_float(csr[e].y);
  dinv[j] = rsqrtf(s);
}

__global__ void wfix_kernel(int2* __restrict__ csr, const float* __restrict__ dinv, int E) {
  int i = blockIdx.x * 256 + threadIdx.x;
  if (i >= E) return;
  int2 m = csr[i];
  csr[i] = make_int2(m.x, __float_as_int(__int_as_float(m.y) * dinv[m.x]));
}

// ---------------- gemm1: branch-free pipelined streaming MFMA ----------------
// One wave owns 32 rows x 64 cols. Hot loop = 24 llm chunks, branch-free,
// 2-buffer (X/Y) explicit software pipeline. Tail = name/type/behav chunks.

__device__ __forceinline__ void mfma24(f32x4 (&acc)[2][4],
                                       const bf16x8& ah0, const bf16x8& al0,
                                       const bf16x8& ah1, const bf16x8& al1,
                                       const bf16x8 (&bh)[4], const bf16x8 (&bl)[4]) {
  #pragma unroll
  for (int ct = 0; ct < 4; ++ct) {
    acc[0][ct] = __builtin_amdgcn_mfma_f32_16x16x32_bf16(ah0, bh[ct], acc[0][ct], 0, 0, 0);
    acc[0][ct] = __builtin_amdgcn_mfma_f32_16x16x32_bf16(ah0, bl[ct], acc[0][ct], 0, 0, 0);
    acc[0][ct] = __builtin_amdgcn_mfma_f32_16x16x32_bf16(al0, bh[ct], acc[0][ct], 0, 0, 0);
  }
  #pragma unroll
  for (int ct = 0; ct < 4; ++ct) {
    acc[1][ct] = __builtin_amdgcn_mfma_f32_16x16x32_bf16(ah1, bh[ct], acc[1][ct], 0, 0, 0);
    acc[1][ct] = __builtin_amdgcn_mfma_f32_16x16x32_bf16(ah1, bl[ct], acc[1][ct], 0, 0, 0);
    acc[1][ct] = __builtin_amdgcn_mfma_f32_16x16x32_bf16(al1, bh[ct], acc[1][ct], 0, 0, 0);
  }
}

__device__ __forceinline__ void loadB(const short* __restrict__ Bh, const short* __restrict__ Bl,
                                      int c, int g, int r16, bf16x8 (&bh)[4], bf16x8 (&bl)[4]) {
  #pragma unroll
  for (int ct = 0; ct < 4; ++ct) {
    size_t o = ((size_t)(c * 4 + g) * 64 + ct * 16 + r16) * 8;
    bh[ct] = *(const bf16x8*)(Bh + o);
    bl[ct] = *(const bf16x8*)(Bl + o);
  }
}

__global__ __launch_bounds__(256, 3) void gemm1_kernel(
    const float* __restrict__ llm, const short* __restrict__ Bh, const short* __restrict__ Bl,
    const int* __restrict__ names, const int* __restrict__ types,
    const float* __restrict__ beh, const float* __restrict__ nemb,
    const float* __restrict__ temb, const float* __restrict__ biasf,
    float* __restrict__ out, int n)
{
  // bijective XCD-aware swizzle (contiguous chunk of blocks per XCD)
  int nwg = gridDim.x;
  int b = blockIdx.x;
  int q = nwg >> 3, r = nwg & 7;
  int xcd = b & 7, idx = b >> 3;
  int swz = (xcd < r ? xcd * (q + 1) : r * (q + 1) + (xcd - r) * q) + idx;

  int w = swz * 4 + (threadIdx.x >> 6);
  int nw = (n + 31) >> 5;
  if (w >= nw) return;
  int lane = threadIdx.x & 63;
  int g = lane >> 4, r16 = lane & 15;
  int base = w * 32;

  int arow0 = base + r16;      if (arow0 > n - 1) arow0 = n - 1;   // clamp: stores are guarded
  int arow1 = base + 16 + r16; if (arow1 > n - 1) arow1 = n - 1;
  int nm0 = names[arow0], nm1 = names[arow1];
  int tp0 = types[arow0], tp1 = types[arow1];

  const float* pA0 = llm + (size_t)arow0 * 768 + g * 4;
  const float* pA1 = llm + (size_t)arow1 * 768 + g * 4;

  f32x4 acc[2][4];
  #pragma unroll
  for (int i = 0; i < 2; ++i)
    #pragma unroll
    for (int j = 0; j < 4; ++j) { acc[i][j][0] = 0.f; acc[i][j][1] = 0.f; acc[i][j][2] = 0.f; acc[i][j][3] = 0.f; }

  // prologue: chunks 0 (X) and 1 (Y)
  float4 X0l = *(const float4*)(pA0 +  0), X0h = *(const float4*)(pA0 + 16);
  float4 X1l = *(const float4*)(pA1 +  0), X1h = *(const float4*)(pA1 + 16);
  float4 Y0l = *(const float4*)(pA0 + 32), Y0h = *(const float4*)(pA0 + 48);
  float4 Y1l = *(const float4*)(pA1 + 32), Y1h = *(const float4*)(pA1 + 48);

  bf16x8 bh[4], bl[4], ah0, al0, ah1, al1;

  #pragma unroll 1
  for (int cc = 0; cc < 11; ++cc) {
    const int c = cc * 2;
    // ---- even sub-body: consume X (chunk c), prefetch chunk c+2 -> X ----
    loadB(Bh, Bl, c, g, r16, bh, bl);
    split8(X0l, X0h, ah0, al0);
    split8(X1l, X1h, ah1, al1);
    X0l = *(const float4*)(pA0 + (c + 2) * 32);      // X dead after splits
    X0h = *(const float4*)(pA0 + (c + 2) * 32 + 16);
    X1l = *(const float4*)(pA1 + (c + 2) * 32);
    X1h = *(const float4*)(pA1 + (c + 2) * 32 + 16);
    mfma24(acc, ah0, al0, ah1, al1, bh, bl);
    // ---- odd sub-body: consume Y (chunk c+1), prefetch chunk c+3 -> Y ----
    loadB(Bh, Bl, c + 1, g, r16, bh, bl);
    split8(Y0l, Y0h, ah0, al0);
    split8(Y1l, Y1h, ah1, al1);
    Y0l = *(const float4*)(pA0 + (c + 3) * 32);
    Y0h = *(const float4*)(pA0 + (c + 3) * 32 + 16);
    Y1l = *(const float4*)(pA1 + (c + 3) * 32);
    Y1h = *(const float4*)(pA1 + (c + 3) * 32 + 16);
    mfma24(acc, ah0, al0, ah1, al1, bh, bl);
  }

  // peeled chunks 22 (X) and 23 (Y) — already in registers
  loadB(Bh, Bl, 22, g, r16, bh, bl);
  split8(X0l, X0h, ah0, al0);
  split8(X1l, X1h, ah1, al1);
  mfma24(acc, ah0, al0, ah1, al1, bh, bl);

  loadB(Bh, Bl, 23, g, r16, bh, bl);
  split8(Y0l, Y0h, ah0, al0);
  split8(Y1l, Y1h, ah1, al1);
  mfma24(acc, ah0, al0, ah1, al1, bh, bl);

  // ---- tail: chunk 24/25 = name_emb, 26 = type|behav[0:16], 27 = behav[16:32]|0 ----
  const float* pN0 = nemb + (size_t)nm0 * 64 + g * 4;
  const float* pN1 = nemb + (size_t)nm1 * 64 + g * 4;
  #pragma unroll
  for (int t = 0; t < 2; ++t) {
    float4 l0 = *(const float4*)(pN0 + t * 32), h0 = *(const float4*)(pN0 + t * 32 + 16);
    float4 l1 = *(const float4*)(pN1 + t * 32), h1 = *(const float4*)(pN1 + t * 32 + 16);
    loadB(Bh, Bl, 24 + t, g, r16, bh, bl);
    split8(l0, h0, ah0, al0);
    split8(l1, h1, ah1, al1);
    mfma24(acc, ah0, al0, ah1, al1, bh, bl);
  }
  {
    float4 l0 = *(const float4*)(temb + (size_t)tp0 * 16 + g * 4);
    float4 h0 = *(const float4*)(beh + (size_t)arow0 * 32 + g * 4);
    float4 l1 = *(const float4*)(temb + (size_t)tp1 * 16 + g * 4);
    float4 h1 = *(const float4*)(beh + (size_t)arow1 * 32 + g * 4);
    loadB(Bh, Bl, 26, g, r16, bh, bl);
    split8(l0, h0, ah0, al0);
    split8(l1, h1, ah1, al1);
    mfma24(acc, ah0, al0, ah1, al1, bh, bl);
  }
  {
    const float4 z = make_float4(0.f, 0.f, 0.f, 0.f);
    float4 l0 = *(const float4*)(beh + (size_t)arow0 * 32 + 16 + g * 4);
    float4 l1 = *(const float4*)(beh + (size_t)arow1 * 32 + 16 + g * 4);
    loadB(Bh, Bl, 27, g, r16, bh, bl);
    split8(l0, z, ah0, al0);
    split8(l1, z, ah1, al1);
    mfma24(acc, ah0, al0, ah1, al1, bh, bl);
  }

  // C/D: col = lane&15 (+16*ct), row = (lane>>4)*4 + reg (+16*rt)
  #pragma unroll
  for (int ct = 0; ct < 4; ++ct) {
    int col = ct * 16 + r16;
    float bf = biasf[col];
    #pragma unroll
    for (int rr = 0; rr < 4; ++rr) {
      int node0 = base + g * 4 + rr;
      if (node0 < n) out[(size_t)node0 * 64 + col] = acc[0][ct][rr] + bf;
      int node1 = base + 16 + g * 4 + rr;
      if (node1 < n) out[(size_t)node1 * 64 + col] = acc[1][ct][rr] + bf;
    }
  }
}

// ---------------- gemm2: h @ W2, streaming, K=64 ----------------

__global__ __launch_bounds__(256, 4) void gemm2_kernel(
    const float* __restrict__ h, const short* __restrict__ B2h, const short* __restrict__ B2l,
    float* __restrict__ out, int n)
{
  int w = blockIdx.x * 4 + (threadIdx.x >> 6);
  int nw = (n + 31) >> 5;
  if (w >= nw) return;
  int lane = threadIdx.x & 63;
  int g = lane >> 4, r16 = lane & 15;
  int base = w * 32;
  int arow0 = base + r16;      if (arow0 > n - 1) arow0 = n - 1;
  int arow1 = base + 16 + r16; if (arow1 > n - 1) arow1 = n - 1;

  f32x4 acc[2][4];
  #pragma unroll
  for (int i = 0; i < 2; ++i)
    #pragma unroll
    for (int j = 0; j < 4; ++j) { acc[i][j][0] = 0.f; acc[i][j][1] = 0.f; acc[i][j][2] = 0.f; acc[i][j][3] = 0.f; }

  #pragma unroll
  for (int c = 0; c < 2; ++c) {
    bf16x8 bh[4], bl[4];
    loadB(B2h, B2l, c, g, r16, bh, bl);
    const float* p0 = h + (size_t)arow0 * 64 + c * 32 + g * 4;
    const float* p1 = h + (size_t)arow1 * 64 + c * 32 + g * 4;
    float4 lo0 = *(const float4*)p0, hi0 = *(const float4*)(p0 + 16);
    float4 lo1 = *(const float4*)p1, hi1 = *(const float4*)(p1 + 16);
    bf16x8 ah0, al0, ah1, al1;
    split8(lo0, hi0, ah0, al0);
    split8(lo1, hi1, ah1, al1);
    mfma24(acc, ah0, al0, ah1, al1, bh, bl);
  }

  #pragma unroll
  for (int ct = 0; ct < 4; ++ct) {
    int col = ct * 16 + r16;
    #pragma unroll
    for (int rr = 0; rr < 4; ++rr) {
      int node0 = base + g * 4 + rr;
      if (node0 < n) out[(size_t)node0 * 64 + col] = acc[0][ct][rr];
      int node1 = base + 16 + g * 4 + rr;
      if (node1 < n) out[(size_t)node1 * 64 + col] = acc[1][ct][rr];
    }
  }
}

// ---------------- aggregation ----------------

__global__ __launch_bounds__(256) void agg_kernel(
    const float* __restrict__ h, const int* __restrict__ colp,
    const int2* __restrict__ csr, const float* __restrict__ dinv,
    const float* __restrict__ bias, float* __restrict__ out, int n)
{
  int wid = threadIdx.x >> 6, lane = threadIdx.x & 63;
  int j = blockIdx.x * 4 + wid;
  if (j >= n) return;
  float dj = dinv[j];
  float hj = h[(size_t)j * 64 + lane];
  int e0 = colp[j], e1 = colp[j + 1];
  float s = 0.0f;
  int e = e0;
  for (; e + 4 <= e1; e += 4) {
    int2 m0 = csr[e], m1 = csr[e + 1], m2 = csr[e + 2], m3 = csr[e + 3];
    float f0 = h[(size_t)m0.x * 64 + lane];
    float f1 = h[(size_t)m1.x * 64 + lane];
    float f2 = h[(size_t)m2.x * 64 + lane];
    float f3 = h[(size_t)m3.x * 64 + lane];
    s = fmaf(__int_as_float(m0.y), f0, s);
    s = fmaf(__int_as_float(m1.y), f1, s);
    s = fmaf(__int_as_float(m2.y), f2, s);
    s = fmaf(__int_as_float(m3.y), f3, s);
  }
  for (; e < e1; ++e) {
    int2 m = csr[e];
    s = fmaf(__int_as_float(m.y), h[(size_t)m.x * 64 + lane], s);
  }
  float acc = bias[lane] + dj * fmaf(dj, hj, s);
  out[(size_t)j * 64 + lane] = fmaxf(acc, 0.0f);
}

// ---------------- pool + classifier ----------------

__global__ __launch_bounds__(256) void pool_kernel(const float* __restrict__ x,
                                                   const int* __restrict__ batch,
                                                   float* __restrict__ pooled, int n) {
  __shared__ float red[4][64];
  __shared__ int range_s[2];
  int gph = blockIdx.x;
  int tid = threadIdx.x, wid = tid >> 6, lane = tid & 63;
  if (tid < 2) {
    int target = gph + tid;
    int lo = 0, hi = n;
    while (lo < hi) { int m = (lo + hi) >> 1; if (batch[m] < target) lo = m + 1; else hi = m; }
    range_s[tid] = lo;
  }
  __syncthreads();
  int lo = range_s[0], hi = range_s[1];
  float acc = 0.0f;
  for (int i = lo + wid; i < hi; i += 4) acc += x[(size_t)i * 64 + lane];
  red[wid][lane] = acc;
  __syncthreads();
  if (tid < 64) {
    float sum = red[0][lane] + red[1][lane] + red[2][lane] + red[3][lane];
    float cntf = (float)(hi - lo);
    pooled[gph * 64 + lane] = sum / fmaxf(cntf, 1.0f);
  }
}

__global__ void cls_kernel(const float* __restrict__ pooled, const float* __restrict__ cw,
                           const float* __restrict__ cb, float* __restrict__ out) {
  int t = threadIdx.x;  // 256 threads = 128 graphs x 2 classes
  int gph = t >> 1, c = t & 1;
  float acc = cb[c];
  #pragma unroll 8
  for (int k = 0; k < 64; ++k) acc = fmaf(pooled[gph * 64 + k], cw[k * 2 + c], acc);
  out[gph * 2 + c] = acc;
}

// ---------------- launch ----------------

extern "C" void kernel_launch(void* const* d_in, const int* in_sizes, int n_in,
                              void* d_out, int out_size, void* d_ws, size_t ws_size,
                              hipStream_t stream) {
  const int*   x_names  = (const int*)  d_in[0];
  const int*   x_types  = (const int*)  d_in[1];
  const float* behav    = (const float*)d_in[2];
  const int*   ei       = (const int*)  d_in[3];
  const float* ew       = (const float*)d_in[4];
  const int*   batch    = (const int*)  d_in[5];
  const float* llm      = (const float*)d_in[6];
  const float* name_emb = (const float*)d_in[7];
  const float* type_emb = (const float*)d_in[8];
  const float* pw       = (const float*)d_in[9];
  const float* pb       = (const float*)d_in[10];
  const float* w1       = (const float*)d_in[11];
  const float* b1       = (const float*)d_in[12];
  const float* w2       = (const float*)d_in[13];
  const float* b2       = (const float*)d_in[14];
  const float* cw       = (const float*)d_in[15];
  const float* cb       = (const float*)d_in[16];

  const int N = in_sizes[0];
  const int E = in_sizes[4];
  const int nb = (N + 255) / 256;
  const int eb = (E + 255) / 256;
  const int nwaves = (N + 31) / 32;
  const int gblocks = (nwaves + 3) / 4;

  char* p = (char*)d_ws;
  auto alloc = [&](size_t bytes) -> void* {
    void* r = (void*)p; p += (bytes + 255) & ~(size_t)255; return r;
  };
  float* dinv   = (float*)alloc((size_t)N * 4);
  int*   cnt    = (int*)  alloc((size_t)N * 4);
  int*   colp   = (int*)  alloc((size_t)(N + 1) * 4);
  int*   fillp  = (int*)  alloc((size_t)N * 4);
  int2*  csr    = (int2*) alloc((size_t)E * 8);
  int*   bsum   = (int*)  alloc((size_t)(nb + 1) * 4);
  short* Bh     = (short*)alloc((size_t)896 * 64 * 2);
  short* Bl     = (short*)alloc((size_t)896 * 64 * 2);
  short* B2h    = (short*)alloc((size_t)64 * 64 * 2);
  short* B2l    = (short*)alloc((size_t)64 * 64 * 2);
  float* biasf  = (float*)alloc((size_t)64 * 4);
  float* bufX   = (float*)alloc((size_t)N * 64 * 4);
  float* bufY   = (float*)alloc((size_t)N * 64 * 4);
  float* pooled = (float*)alloc((size_t)128 * 64 * 4);
  (void)ws_size; (void)n_in; (void)out_size;

  prep1_kernel<<<(896 * 64 + 64 + 255) / 256, 256, 0, stream>>>(pw, pb, w1, Bh, Bl, biasf);
  prep2_kernel<<<16, 256, 0, stream>>>(w2, B2h, B2l);
  hipMemsetAsync(cnt, 0, (size_t)N * 4, stream);
  cnt_kernel<<<eb, 256, 0, stream>>>(ei, cnt, E);
  scan_blk<<<nb, 256, 0, stream>>>(cnt, colp, bsum, N);
  scan_top<<<1, 512, 0, stream>>>(bsum, colp, nb, N);
  scan_add<<<nb, 256, 0, stream>>>(colp, fillp, bsum, N);
  fill_kernel<<<eb, 256, 0, stream>>>(ei, ew, fillp, csr, E);
  degsum_kernel<<<nb, 256, 0, stream>>>(colp, csr, dinv, N);
  wfix_kernel<<<eb, 256, 0, stream>>>(csr, dinv, E);

  gemm1_kernel<<<gblocks, 256, 0, stream>>>(llm, Bh, Bl, x_names, x_types, behav,
                                            name_emb, type_emb, biasf, bufX, N);
  agg_kernel<<<(N + 3) / 4, 256, 0, stream>>>(bufX, colp, csr, dinv, b1, bufY, N);
  gemm2_kernel<<<gblocks, 256, 0, stream>>>(bufY, B2h, B2l, bufX, N);
  agg_kernel<<<(N + 3) / 4, 256, 0, stream>>>(bufX, colp, csr, dinv, b2, bufY, N);
  pool_kernel<<<128, 256, 0, stream>>>(bufY, batch, pooled, N);
  cls_kernel<<<1, 256, 0, stream>>>(pooled, cw, cb, (float*)d_out);
}